// Round 8
// baseline (30.964 us; speedup 1.0000x reference)
//
#include <hip/hip_runtime.h>

// SoftDiceLoss: predictions [B=8, C=16, H=512, W=512] fp32, targets [B,H,W] int32.
// out[b] = -(1/C) * sum_c (2*overlap[b,c] + 1) / (i_sum[b,c] + count[b,c] + 1)
//
// Stage 1: 1024 blocks = (8 batches x 128 slabs of 2048 positions) x 256 thr
//   = 4 blocks/CU = 16 waves/CU, one residency round (launch_bounds(256,4)
//   caps VGPR at 128 so loads can pipeline ~2 classes ahead).
//   Each thread owns 8 positions; targets packed 4 bits each into ONE u32
//   (tpack). The 16 pred class-segments stream SEQUENTIALLY (2 float4 in
//   flight per thread per class). Per class: 5-VALU exact nibble==c mask
//   on tpack; count = popcount. Wave reduce = DPP row_shr/row_bcast (pure
//   VALU, zero DS ops) -> lane 63 -> LDS -> partial[comp][block] in d_ws.
// Stage 2: 8 blocks x 128 threads: thread t reduces one slab-column;
//   2-wave DPP reduce + LDS combine; thread 0 computes the 16 fracs.

constexpr int  C_CLS   = 16;
constexpr long HW      = 512L * 512L;   // 262144 positions per (b,c) plane
constexpr int  BATCH   = 8;
constexpr int  SLAB    = 2048;          // positions per block
constexpr int  SLABS   = (int)(HW / SLAB);   // 128 per batch
constexpr int  NBLK    = BATCH * SLABS;      // 1024
constexpr int  NPART   = 3 * C_CLS;          // 48 components

// Full wave64 sum via DPP (rocPRIM pattern). Result valid in lane 63.
__device__ __forceinline__ float wave_reduce_dpp(float x) {
    int t;
    t = __builtin_amdgcn_update_dpp(0, __float_as_int(x), 0x111, 0xf, 0xf, true); // row_shr:1
    x += __int_as_float(t);
    t = __builtin_amdgcn_update_dpp(0, __float_as_int(x), 0x112, 0xf, 0xf, true); // row_shr:2
    x += __int_as_float(t);
    t = __builtin_amdgcn_update_dpp(0, __float_as_int(x), 0x114, 0xf, 0xf, true); // row_shr:4
    x += __int_as_float(t);
    t = __builtin_amdgcn_update_dpp(0, __float_as_int(x), 0x118, 0xf, 0xf, true); // row_shr:8
    x += __int_as_float(t);
    t = __builtin_amdgcn_update_dpp(0, __float_as_int(x), 0x142, 0xa, 0xf, true); // row_bcast:15
    x += __int_as_float(t);
    t = __builtin_amdgcn_update_dpp(0, __float_as_int(x), 0x143, 0xc, 0xf, true); // row_bcast:31
    x += __int_as_float(t);
    return x;
}

__global__ __launch_bounds__(256, 4)
void dice_partial_kernel(const float* __restrict__ pred,
                         const int*   __restrict__ tgt,
                         float*       __restrict__ partial) {
    const int g    = blockIdx.x;
    const int slab = g & (SLABS - 1);
    const int b    = g >> 7;
    const int tid  = threadIdx.x;
    const int lane = tid & 63;
    const int wv   = tid >> 6;

    const long sbase = (long)slab * SLAB;        // within plane
    const int* tb = tgt + (long)b * HW + sbase;

    // pack this thread's 8 target values into one u32 (4 bits each)
    unsigned tpack = 0u;
#pragma unroll
    for (int j = 0; j < 2; ++j) {
        const int4 tv = *reinterpret_cast<const int4*>(tb + j * 1024 + tid * 4);
        const unsigned nib = (unsigned)tv.x | ((unsigned)tv.y << 4)
                           | ((unsigned)tv.z << 8) | ((unsigned)tv.w << 12);
        tpack |= nib << (16 * j);
    }

    const float* pb = pred + (long)b * C_CLS * HW + sbase;

    __shared__ float sm[4][NPART];

#pragma unroll
    for (int c = 0; c < C_CLS; ++c) {
        // exact per-nibble (t==c) mask: bit 4i of m = match at position i
        unsigned x = tpack ^ ((unsigned)c * 0x11111111u);
        x |= x >> 2;
        x |= x >> 1;
        const unsigned m = ~x & 0x11111111u;

        float isum = 0.f, ov = 0.f;
#pragma unroll
        for (int j = 0; j < 2; ++j) {
            const float4 p = *reinterpret_cast<const float4*>(
                pb + (long)c * HW + j * 1024 + tid * 4);
            const unsigned mb = m >> (16 * j);
            isum += (p.x + p.y) + (p.z + p.w);
            ov   += ((mb & 0x0001u) ? p.x : 0.f) + ((mb & 0x0010u) ? p.y : 0.f)
                  + ((mb & 0x0100u) ? p.z : 0.f) + ((mb & 0x1000u) ? p.w : 0.f);
        }
        float cntf = (float)__popc(m);

        isum = wave_reduce_dpp(isum);
        ov   = wave_reduce_dpp(ov);
        cntf = wave_reduce_dpp(cntf);
        if (lane == 63) {
            sm[wv][c * 3 + 0] = isum;
            sm[wv][c * 3 + 1] = ov;
            sm[wv][c * 3 + 2] = cntf;
        }
    }

    __syncthreads();
    if (tid < NPART) {
        // component-major layout: partial[comp][block] for coalesced stage-2
        partial[(long)tid * NBLK + g] =
            (sm[0][tid] + sm[1][tid]) + (sm[2][tid] + sm[3][tid]);
    }
}

__global__ __launch_bounds__(128)
void dice_final_kernel(const float* __restrict__ partial,
                       float*       __restrict__ out) {
    const int b    = blockIdx.x;
    const int t    = threadIdx.x;    // one slab-column per thread (128 slabs)
    const int lane = t & 63;
    const int wv   = t >> 6;

    float acc[NPART];
#pragma unroll
    for (int k = 0; k < NPART; ++k)
        acc[k] = partial[(long)k * NBLK + b * SLABS + t];

#pragma unroll
    for (int k = 0; k < NPART; ++k)
        acc[k] = wave_reduce_dpp(acc[k]);   // valid in lane 63 of each wave

    __shared__ float sm[2][NPART];
    if (lane == 63) {
#pragma unroll
        for (int k = 0; k < NPART; ++k) sm[wv][k] = acc[k];
    }
    __syncthreads();

    if (t == 0) {
        float s = 0.f;
#pragma unroll
        for (int c = 0; c < C_CLS; ++c) {
            const float is = sm[0][c * 3 + 0] + sm[1][c * 3 + 0];
            const float o  = sm[0][c * 3 + 1] + sm[1][c * 3 + 1];
            const float cn = sm[0][c * 3 + 2] + sm[1][c * 3 + 2];
            s += (2.f * o + 1.f) / (is + cn + 1.f);
        }
        out[b] = -s * (1.f / (float)C_CLS);
    }
}

extern "C" void kernel_launch(void* const* d_in, const int* in_sizes, int n_in,
                              void* d_out, int out_size, void* d_ws, size_t ws_size,
                              hipStream_t stream) {
    const float* pred = (const float*)d_in[0];
    const int*   tgt  = (const int*)d_in[1];
    float*       out  = (float*)d_out;
    float*       partial = (float*)d_ws;   // 48 * 1024 * 4 B = 196608 B

    dice_partial_kernel<<<NBLK, 256, 0, stream>>>(pred, tgt, partial);
    dice_final_kernel<<<BATCH, 128, 0, stream>>>(partial, out);
}